// Round 3
// baseline (27.568 us; speedup 1.0000x reference)
//
#include <hip/hip_runtime.h>

// Rank IGR Loss — sorted-tile + suffix-sum algorithm (O(N^2) -> O(N log N)).
//
// Condition d[j]-d[i] >= 1 is monotone in d[j] (f32 sub is monotone), so with
// each 128-elem tile sorted by masked d' (= pos ? d : -1e30), the satisfying
// j's form a suffix. K1 rank-sorts tiles and stores inclusive suffix sums of
// w1 = exp(G1*prob), w2 = exp(G2*iou); K2 binary-searches (exact same f32
// compare) and accumulates suf1[k], suf2[k], (TS-k). Non-pos j sort to the
// front and never satisfy the condition; non-pos i have v1=v2=0 weights.

#define G1 3.0f
#define G2 1.0f

constexpr int B  = 16;
constexpr int N  = 2048;
constexpr int TS = 128;            // sorted-tile size
constexpr int NT = N / TS;         // 16 tiles per batch
constexpr int K2S = 8;             // i-splits per batch
constexpr int K2B = B * K2S;       // 128 search blocks

// ws layout: [0] counter | [64] part[K2B*3] dbl | [4096] 6 x f32[B*N]
//   dd, v1a, v2a, ssd, suf1, suf2   (total ~776 KB)

__global__ void __launch_bounds__(TS)
prep_kernel(const float* __restrict__ cls, const int* __restrict__ label_cls,
            const float* __restrict__ label_loc, const float* __restrict__ pred,
            const float* __restrict__ tgt,
            float* __restrict__ dd, float* __restrict__ v1a, float* __restrict__ v2a,
            float* __restrict__ ssd, float* __restrict__ suf1, float* __restrict__ suf2,
            unsigned* __restrict__ counter) {
  __shared__ uint4 stile[TS];   // {idx, ordkey(d'), w1 bits, w2 bits}

  if (blockIdx.x == 0 && threadIdx.x == 0) *counter = 0u;  // reset for K2 election

  const int b  = blockIdx.x >> 4;          // / NT
  const int jc = blockIdx.x & (NT - 1);
  const int t  = threadIdx.x;
  const int n  = jc * TS + t;
  const int gn = b * N + n;

  const float tx1 = tgt[b * 4 + 0], ty1 = tgt[b * 4 + 1];
  const float tx2 = tgt[b * 4 + 2], ty2 = tgt[b * 4 + 3];
  const float ta  = (tx2 - tx1) * (ty2 - ty1);
  const float tcx = (tx1 + tx2) * 0.5f, tcy = (ty1 + ty2) * 0.5f;

  const float* __restrict__ pb = pred      + (size_t)b * 4 * N;
  const float* __restrict__ lb = label_loc + (size_t)b * 4 * N;

  float x1 = pb[n], y1 = pb[N + n], x2 = pb[2 * N + n], y2 = pb[3 * N + n];
  float ww = fmaxf(fminf(tx2, x2) - fmaxf(tx1, x1), 0.f);
  float hh = fmaxf(fminf(ty2, y2) - fmaxf(ty1, y1), 0.f);
  float inter = ww * hh;
  float iou  = inter / ((x2 - x1) * (y2 - y1) + ta - inter);
  float prob = __expf(cls[(size_t)gn * 2 + 1]);
  bool  pos  = label_cls[gn] > 0;
  float cx = lb[n] + tx1, cy = lb[N + n] + ty1;
  float dx = cx - tcx, dy = cy - tcy;
  float d  = sqrtf(dx * dx + dy * dy);

  float dm = pos ? d : -1e30f;             // masked d: !pos never satisfies cond
  float w1 = __expf(G1 * prob);
  float w2 = __expf(G2 * iou);

  dd[gn]  = d;
  v1a[gn] = pos ? __expf(-G1 * prob) : 0.f;   // >0 iff pos (exp never underflows here)
  v2a[gn] = pos ? __expf(-G2 * iou)  : 0.f;

  // order-preserving float->uint transform, index in low 32 bits for total order
  unsigned u = __float_as_uint(dm);
  u ^= (u & 0x80000000u) ? 0xFFFFFFFFu : 0x80000000u;
  stile[t] = make_uint4((unsigned)t, u, __float_as_uint(w1), __float_as_uint(w2));
  __syncthreads();

  const unsigned long long mykey = ((unsigned long long)u << 32) | (unsigned)t;
  int rank = 0;
  float s1 = 0.f, s2 = 0.f;
#pragma unroll 8
  for (int q = 0; q < TS; ++q) {
    uint4 v = stile[q];                       // LDS broadcast read
    unsigned long long kq = ((unsigned long long)v.y << 32) | v.x;
    bool lt = kq < mykey;
    rank += lt ? 1 : 0;
    s1 += lt ? 0.f : __uint_as_float(v.z);    // inclusive suffix at my rank
    s2 += lt ? 0.f : __uint_as_float(v.w);
  }
  const int outp = b * N + jc * TS + rank;    // rank is a bijection -> full fill
  ssd[outp]  = dm;
  suf1[outp] = s1;
  suf2[outp] = s2;
}

__global__ void __launch_bounds__(256)
search_kernel(const float* __restrict__ dd, const float* __restrict__ v1a,
              const float* __restrict__ v2a,
              const float* __restrict__ ssd, const float* __restrict__ suf1,
              const float* __restrict__ suf2,
              const int* __restrict__ dataset_id,
              double* __restrict__ part, unsigned* __restrict__ counter,
              float* __restrict__ out) {
  __shared__ float lsd[N], ls1[N], ls2[N];   // 24 KB
  __shared__ double red[3][4];
  __shared__ double bl1[B], bl2[B], bval[B];
  __shared__ unsigned s_last;

  const int b  = blockIdx.x >> 3;
  const int ib = blockIdx.x & (K2S - 1);
  const int t  = threadIdx.x;

  {  // stage sorted structures (coalesced float4)
    const float4* g1 = (const float4*)(ssd  + (size_t)b * N);
    const float4* g2 = (const float4*)(suf1 + (size_t)b * N);
    const float4* g3 = (const float4*)(suf2 + (size_t)b * N);
    float4* p1l = (float4*)lsd; float4* p2l = (float4*)ls1; float4* p3l = (float4*)ls2;
#pragma unroll
    for (int r = 0; r < (N / 4) / 256; ++r) {
      int idx = r * 256 + t;
      p1l[idx] = g1[idx]; p2l[idx] = g2[idx]; p3l[idx] = g3[idx];
    }
  }

  const int   i   = b * N + ib * 256 + t;
  const float di  = dd[i];
  const float v1i = v1a[i];
  const float v2i = v2a[i];
  __syncthreads();

  double s1d = 0.0, s2d = 0.0;
  int cnt = 0;
#pragma unroll
  for (int tile = 0; tile < NT; ++tile) {
    const int base = tile * TS;
    // branchless lower_bound on monotone pred: (d_sorted - di >= 1.0f)
    int k = 0;
#pragma unroll
    for (int w = TS >> 1; w > 0; w >>= 1)
      k += (lsd[base + k + w - 1] - di >= 1.0f) ? 0 : w;
    k += (lsd[base + k] - di >= 1.0f) ? 0 : 1;     // k in [0, TS]
    const bool any = (k < TS);
    const int  idx = base + (any ? k : 0);         // clamp for safe LDS read
    s1d += (double)(any ? ls1[idx] : 0.f);
    s2d += (double)(any ? ls2[idx] : 0.f);
    cnt += TS - k;                                 // all suffix elems are pos & cond
  }

  double p1 = (double)v1i * s1d;
  double p2 = (double)v2i * s2d;
  double pc = (v1i > 0.f) ? (double)cnt : 0.0;     // v1i>0 <=> pos[i]

  for (int off = 32; off; off >>= 1) {
    p1 += __shfl_down(p1, off);
    p2 += __shfl_down(p2, off);
    pc += __shfl_down(pc, off);
  }
  const int wv = t >> 6, lane = t & 63;
  if (lane == 0) { red[0][wv] = p1; red[1][wv] = p2; red[2][wv] = pc; }
  __syncthreads();
  if (t == 0) {
    part[(size_t)blockIdx.x * 3 + 0] = red[0][0] + red[0][1] + red[0][2] + red[0][3];
    part[(size_t)blockIdx.x * 3 + 1] = red[1][0] + red[1][1] + red[1][2] + red[1][3];
    part[(size_t)blockIdx.x * 3 + 2] = red[2][0] + red[2][1] + red[2][2] + red[2][3];
    __threadfence();                               // publish partials (device scope)
    unsigned old = atomicAdd(counter, 1u);
    s_last = (old == (unsigned)(K2B - 1)) ? 1u : 0u;
  }
  __syncthreads();
  if (s_last) {                                    // last block finalizes
    __threadfence();                               // acquire: invalidate stale lines
    double q1 = 0, q2 = 0, qc = 0;
    if (t < K2B) {
      const volatile double* vp = part;
      q1 = vp[t * 3 + 0]; q2 = vp[t * 3 + 1]; qc = vp[t * 3 + 2];
    }
    for (int off = 4; off; off >>= 1) {            // sum groups of 8 (one batch)
      q1 += __shfl_down(q1, off);
      q2 += __shfl_down(q2, off);
      qc += __shfl_down(qc, off);
    }
    if (t < K2B && (t & 7) == 0) {
      int bb = t >> 3;
      bool valid = (dataset_id[bb] != 1) && (qc > 0.0);
      double denom = fmax(qc, 1.0);
      bl1[bb]  = valid ? q1 / denom : 0.0;
      bl2[bb]  = valid ? q2 / denom : 0.0;
      bval[bb] = valid ? 1.0 : 0.0;
    }
    __syncthreads();
    if (t == 0) {
      double nv = 0, f1 = 0, f2 = 0;
      for (int bb = 0; bb < B; ++bb) { nv += bval[bb]; f1 += bl1[bb]; f2 += bl2[bb]; }
      out[0] = (float)((nv > 0) ? f1 / nv : 0.0);
      out[1] = (float)((nv > 0) ? f2 / nv : 0.0);
    }
  }
}

extern "C" void kernel_launch(void* const* d_in, const int* in_sizes, int n_in,
                              void* d_out, int out_size, void* d_ws, size_t ws_size,
                              hipStream_t stream) {
  const float* cls       = (const float*)d_in[0];
  const int*   label_cls = (const int*)d_in[1];
  const float* label_loc = (const float*)d_in[2];
  const float* pred      = (const float*)d_in[3];
  const float* tgt       = (const float*)d_in[4];
  const int*   dset      = (const int*)d_in[5];

  char*     ws      = (char*)d_ws;
  unsigned* counter = (unsigned*)ws;
  double*   part    = (double*)(ws + 64);
  float*    dd      = (float*)(ws + 4096);
  float*    v1a     = dd  + (size_t)B * N;
  float*    v2a     = v1a + (size_t)B * N;
  float*    ssd     = v2a + (size_t)B * N;
  float*    suf1    = ssd + (size_t)B * N;
  float*    suf2    = suf1 + (size_t)B * N;

  prep_kernel<<<B * NT, TS, 0, stream>>>(cls, label_cls, label_loc, pred, tgt,
                                         dd, v1a, v2a, ssd, suf1, suf2, counter);
  search_kernel<<<K2B, 256, 0, stream>>>(dd, v1a, v2a, ssd, suf1, suf2,
                                         dset, part, counter, (float*)d_out);
}